// Round 26
// baseline (11598.516 us; speedup 1.0000x reference)
//
#include <hip/hip_runtime.h>

typedef unsigned short u16;
typedef unsigned int u32;

#define TBW 128   // threads per block (2 waves)

// ---- graph constants (verbatim from reference) ----
__device__ static constexpr int PRED[6][2] = {{0,3},{1,5},{0,4},{2,7},{1,6},{2,8}};
__device__ static constexpr int EDG [6][2] = {{0,1},{0,2},{1,0},{1,2},{2,0},{2,1}};
__device__ static constexpr int INCM[3][2] = {{2,4},{0,5},{1,3}};

struct WPtrs { const float* p[32]; };

// ws layout (floats): ef [96][B] @0 ; h [384][B] @96B ; qk [12][B] @480B ; total 492*B

// =====================================================================
// Pass MPEA (fused): grid (B/TBW, 3), o = blockIdx.y.
// r26: hst round-trips removed (static hh/xm indices via unrolled t).
// =====================================================================
extern "C" __global__ void __launch_bounds__(TBW, 2)
pass_mpea(const float* __restrict__ obs, const float* __restrict__ ag,
          const float* __restrict__ g, WPtrs wp, float* __restrict__ ws, int B)
{
  __shared__ float xs[18*TBW];
  __shared__ float x0b[32*TBW];
  __shared__ float wbuf[512];
  __shared__ float wv[1024];
  const int tid = threadIdx.x;
  const int s = blockIdx.x*TBW + tid;
  const int o = blockIdx.y;
  const bool live = (s < B);

  if (live) {
    #pragma unroll
    for(int k=0;k<9;k++) xs[k*TBW+tid] = g[s*9+k] - ag[s*9+k];
    #pragma unroll
    for(int oo=0;oo<3;oo++)
      #pragma unroll
      for(int i=0;i<3;i++) xs[(9+oo*3+i)*TBW+tid] = obs[s*55+10+15*oo+i];
  } else {
    #pragma unroll
    for(int k=0;k<9;k++) xs[k*TBW+tid] = 0.f;
    #pragma unroll
    for(int k=0;k<9;k++) xs[(9+k)*TBW+tid] = 0.f;
  }
  for(int i=tid;i<256;i+=TBW)
    *(float4*)&wv[i*4] = *(const float4*)&wp.p[8][i*4];

  const float* W1=wp.p[0]; const float* B1=wp.p[1];
  const float* W2=wp.p[2]; const float* B2=wp.p[3];
  float* ef = ws;

  float q0,k0,q1,k1;
  float o32[32];

  #pragma unroll
  for(int slot=0;slot<2;slot++){
    const int e = INCM[o][slot];
    #pragma unroll
    for(int m=0;m<32;m++) o32[m]=B2[m];

    for(int c16=0;c16<16;c16++){
      __syncthreads();
      for(int i=tid;i<32;i+=TBW){
        int k=i>>2, q=i&3;
        *(float4*)&wbuf[k*16+q*4] = *(const float4*)&W1[k*256 + c16*16 + q*4];
      }
      __syncthreads();
      float hh[16];
      #pragma unroll
      for(int n=0;n<16;n++) hh[n]=B1[c16*16+n];
      {
        float4 w0 = *(const float4*)&wbuf[0];
        float4 w1 = *(const float4*)&wbuf[4];
        float4 w2 = *(const float4*)&wbuf[8];
        float4 w3 = *(const float4*)&wbuf[12];
        #pragma unroll
        for(int k=0;k<8;k++){
          const int row = (k<2) ? PRED[e][k] : (k<5) ? (9+3*EDG[e][0]+(k-2)) : (9+3*EDG[e][1]+(k-5));
          float xv = xs[row*TBW+tid];
          float4 n0,n1,n2,n3;
          if (k<7){
            n0 = *(const float4*)&wbuf[(k+1)*16+0];
            n1 = *(const float4*)&wbuf[(k+1)*16+4];
            n2 = *(const float4*)&wbuf[(k+1)*16+8];
            n3 = *(const float4*)&wbuf[(k+1)*16+12];
          } else { n0=w0; n1=w1; n2=w2; n3=w3; }
          hh[0]=fmaf(xv,w0.x,hh[0]);  hh[1]=fmaf(xv,w0.y,hh[1]);
          hh[2]=fmaf(xv,w0.z,hh[2]);  hh[3]=fmaf(xv,w0.w,hh[3]);
          hh[4]=fmaf(xv,w1.x,hh[4]);  hh[5]=fmaf(xv,w1.y,hh[5]);
          hh[6]=fmaf(xv,w1.z,hh[6]);  hh[7]=fmaf(xv,w1.w,hh[7]);
          hh[8]=fmaf(xv,w2.x,hh[8]);  hh[9]=fmaf(xv,w2.y,hh[9]);
          hh[10]=fmaf(xv,w2.z,hh[10]); hh[11]=fmaf(xv,w2.w,hh[11]);
          hh[12]=fmaf(xv,w3.x,hh[12]); hh[13]=fmaf(xv,w3.y,hh[13]);
          hh[14]=fmaf(xv,w3.z,hh[14]); hh[15]=fmaf(xv,w3.w,hh[15]);
          w0=n0; w1=n1; w2=n2; w3=n3;
        }
      }
      __syncthreads();
      for(int i=tid;i<128;i+=TBW){
        int t=i>>3, q=i&7;
        *(float4*)&wbuf[t*32+q*4] = *(const float4*)&W2[(c16*16+t)*32 + q*4];
      }
      __syncthreads();
      // layer 2: static hh index (t unrolled), reg-batched rows
      #pragma unroll
      for(int g4=0;g4<4;g4++){
        #pragma unroll
        for(int t=0;t<4;t++){
          float hv = fmaxf(hh[g4*4+t],0.f);
          const float* w = &wbuf[(g4*4+t)*32];
          float4 Wv[8];
          #pragma unroll
          for(int q=0;q<8;q++) Wv[q] = *(const float4*)&w[q*4];
          #pragma unroll
          for(int q=0;q<8;q++){
            o32[q*4+0]=fmaf(hv,Wv[q].x,o32[q*4+0]);
            o32[q*4+1]=fmaf(hv,Wv[q].y,o32[q*4+1]);
            o32[q*4+2]=fmaf(hv,Wv[q].z,o32[q*4+2]);
            o32[q*4+3]=fmaf(hv,Wv[q].w,o32[q*4+3]);
          }
        }
      }
    }
    float qt=wp.p[5][0], kt=wp.p[7][0];
    #pragma unroll
    for(int k=0;k<32;k++){ qt=fmaf(o32[k],wp.p[4][k],qt); kt=fmaf(o32[k],wp.p[6][k],kt); }
    if(slot==0){
      q0=qt; k0=kt;
      #pragma unroll
      for(int n=0;n<32;n++) x0b[n*TBW+tid]=o32[n];
    } else {
      q1=qt; k1=kt;
    }
  }

  float s00=q0*k0, s01=q0*k1, s10=q1*k0, s11=q1*k1;
  float m0=fmaxf(s00,s01), m1=fmaxf(s10,s11);
  float e00=expf(s00-m0), e01=expf(s01-m0), e10=expf(s10-m1), e11=expf(s11-m1);
  float d0=e00+e01, d1=e10+e11;
  float c0=e00/d0+e10/d1, c1=e01/d0+e11/d1;

  float xm[32];
  #pragma unroll
  for(int n=0;n<32;n++) xm[n] = fmaf(c0, x0b[n*TBW+tid], c1*o32[n]);
  float vt[32];
  #pragma unroll
  for(int n=0;n<32;n++) vt[n] = 2.f*wp.p[9][n];
  #pragma unroll
  for(int k=0;k<32;k++){          // static xm index (fully unrolled)
    float a = xm[k];
    const float* w = &wv[k*32];
    float4 Wv[8];
    #pragma unroll
    for(int q=0;q<8;q++) Wv[q] = *(const float4*)&w[q*4];
    #pragma unroll
    for(int q=0;q<8;q++){
      vt[q*4+0]=fmaf(a,Wv[q].x,vt[q*4+0]);
      vt[q*4+1]=fmaf(a,Wv[q].y,vt[q*4+1]);
      vt[q*4+2]=fmaf(a,Wv[q].z,vt[q*4+2]);
      vt[q*4+3]=fmaf(a,Wv[q].w,vt[q*4+3]);
    }
  }
  if (live) {
    #pragma unroll
    for(int n=0;n<32;n++) ef[(o*32+n)*B + s] = vt[n];
  }
}

// =====================================================================
// Pass B1 (phi): grid (B/TBW, 6), combo = blockIdx.y.
// r26: xin[61] REGISTER-RESIDENT (loaded once from global; k-loop fully
// unrolled for static indexing) — removes 976 redundant ds_reads/combo.
// hst round-trip removed (static hh via unrolled g,t). LDS = wbuf 4KB.
// Accum order (c16, k asc, g,t asc) unchanged: bit-identical.
// =====================================================================
extern "C" __global__ void __launch_bounds__(TBW, 2)
pass_phi(const float* __restrict__ obs, const float* __restrict__ act,
         WPtrs wp, float* __restrict__ ws, int B)
{
  __shared__ float wbuf[1024];    // W1 chunk [61][16] / W2 chunk [16][64]
  const int tid = threadIdx.x;
  const int s = blockIdx.x*TBW + tid;
  const int combo = blockIdx.y;
  const int set = combo/3, j = combo%3;
  const bool live = (s < B);

  const float* ef = ws;
  float* h  = ws + 96*B;
  float* qk = ws + 480*B;

  float xin[61];
  if (live) {
    #pragma unroll
    for(int k=0;k<4;k++)  xin[k]    = act[s*4+k];
    #pragma unroll
    for(int k=0;k<10;k++) xin[4+k]  = obs[s*55+k];
    #pragma unroll
    for(int k=0;k<15;k++) xin[14+k] = obs[s*55+10+15*j+k];
    #pragma unroll
    for(int k=0;k<32;k++) xin[29+k] = ef[(j*32+k)*B + s];
  } else {
    #pragma unroll
    for(int k=0;k<61;k++) xin[k]=0.f;
  }

  const float* pw1 = wp.p[set?14:10]; const float* pb1 = wp.p[set?15:11];
  const float* pw2 = wp.p[set?16:12]; const float* pb2 = wp.p[set?17:13];

  float o64[64];
  #pragma unroll
  for(int n=0;n<64;n++) o64[n]=pb2[n];

  for(int c16=0;c16<16;c16++){
    __syncthreads();                       // protect wbuf
    for(int i=tid;i<244;i+=TBW){
      int k=i>>2, q=i&3;
      *(float4*)&wbuf[k*16+q*4] = *(const float4*)&pw1[k*256 + c16*16 + q*4];
    }
    __syncthreads();
    // ---- layer 1: fully unrolled, xin static, weights direct (ILP from unroll) ----
    float hh[16];
    #pragma unroll
    for(int n=0;n<16;n++) hh[n]=pb1[c16*16+n];
    #pragma unroll
    for(int k=0;k<61;k++){
      float xv = xin[k];
      float4 w0 = *(const float4*)&wbuf[k*16+0];
      float4 w1 = *(const float4*)&wbuf[k*16+4];
      float4 w2 = *(const float4*)&wbuf[k*16+8];
      float4 w3 = *(const float4*)&wbuf[k*16+12];
      hh[0]=fmaf(xv,w0.x,hh[0]);  hh[1]=fmaf(xv,w0.y,hh[1]);
      hh[2]=fmaf(xv,w0.z,hh[2]);  hh[3]=fmaf(xv,w0.w,hh[3]);
      hh[4]=fmaf(xv,w1.x,hh[4]);  hh[5]=fmaf(xv,w1.y,hh[5]);
      hh[6]=fmaf(xv,w1.z,hh[6]);  hh[7]=fmaf(xv,w1.w,hh[7]);
      hh[8]=fmaf(xv,w2.x,hh[8]);  hh[9]=fmaf(xv,w2.y,hh[9]);
      hh[10]=fmaf(xv,w2.z,hh[10]); hh[11]=fmaf(xv,w2.w,hh[11]);
      hh[12]=fmaf(xv,w3.x,hh[12]); hh[13]=fmaf(xv,w3.y,hh[13]);
      hh[14]=fmaf(xv,w3.z,hh[14]); hh[15]=fmaf(xv,w3.w,hh[15]);
    }
    __syncthreads();                       // before overwriting wbuf
    for(int i=tid;i<256;i+=TBW){
      int t=i>>4, q=i&15;
      *(float4*)&wbuf[t*64+q*4] = *(const float4*)&pw2[(c16*16+t)*64 + q*4];
    }
    __syncthreads();
    // ---- layer 2: static hh (g,t unrolled), reg-batched rows ----
    #pragma unroll
    for(int g=0;g<4;g++){
      #pragma unroll
      for(int t=0;t<4;t++){
        float hv = fmaxf(hh[g*4+t],0.f);
        const float* w = &wbuf[(g*4+t)*64];
        float4 Wv[16];
        #pragma unroll
        for(int q=0;q<16;q++) Wv[q] = *(const float4*)&w[q*4];
        #pragma unroll
        for(int q=0;q<16;q++){
          o64[q*4+0]=fmaf(hv,Wv[q].x,o64[q*4+0]);
          o64[q*4+1]=fmaf(hv,Wv[q].y,o64[q*4+1]);
          o64[q*4+2]=fmaf(hv,Wv[q].z,o64[q*4+2]);
          o64[q*4+3]=fmaf(hv,Wv[q].w,o64[q*4+3]);
        }
      }
    }
  }
  if (live) {
    float qj=wp.p[19][0], kj=wp.p[21][0];
    #pragma unroll
    for(int n=0;n<64;n++){
      float hv = fmaxf(o64[n],0.f);
      h[(combo*64+n)*B + s] = hv;
      qj = fmaf(hv, wp.p[18][n], qj);
      kj = fmaf(hv, wp.p[20][n], kj);
    }
    qk[(combo*2+0)*B + s] = qj;
    qk[(combo*2+1)*B + s] = kj;
  }
}

// =====================================================================
// Pass B2 (rho): grid (B/TBW, 2). r26: hst removed (static t64/s64 via
// unrolled g4,t), reg-batched rows (r25).
// =====================================================================
extern "C" __global__ void __launch_bounds__(TBW, 2)
pass_rho(WPtrs wp, const float* __restrict__ ws, float* __restrict__ out, int B)
{
  __shared__ float wbuf[4096];
  const int tid = threadIdx.x;
  const int s = blockIdx.x*TBW + tid;
  const int set = blockIdx.y;
  const bool live = (s < B);

  const float* h  = ws + 96*B;
  const float* qk = ws + 480*B;

  for(int i=tid;i<1024;i+=TBW)
    *(float4*)&wbuf[i*4] = *(const float4*)&wp.p[22][i*4];
  __syncthreads();

  float cw0=0.f, cw1=0.f, cw2=0.f;
  float t64[64];
  if (live) {
    float qn[3], kn[3];
    #pragma unroll
    for(int t=0;t<3;t++){
      qn[t] = qk[((set*3+t)*2+0)*B + s];
      kn[t] = qk[((set*3+t)*2+1)*B + s];
    }
    #pragma unroll
    for(int i=0;i<3;i++){
      float t0=qn[i]*kn[0], t1=qn[i]*kn[1], t2=qn[i]*kn[2];
      float mm=fmaxf(fmaxf(t0,t1),t2);
      float e0=expf(t0-mm), e1=expf(t1-mm), e2=expf(t2-mm);
      float dd=e0+e1+e2;
      cw0 += e0/dd; cw1 += e1/dd; cw2 += e2/dd;
    }
    #pragma unroll
    for(int n=0;n<64;n++){
      t64[n] = cw0*h[((set*3+0)*64+n)*B+s]
             + cw1*h[((set*3+1)*64+n)*B+s]
             + cw2*h[((set*3+2)*64+n)*B+s];
    }
  } else {
    #pragma unroll
    for(int n=0;n<64;n++) t64[n]=0.f;
  }

  float s64[64];
  #pragma unroll
  for(int n=0;n<64;n++) s64[n] = 3.f*wp.p[23][n];
  #pragma unroll
  for(int k=0;k<64;k++){            // static t64 index (fully unrolled)
    float tv = t64[k];
    const float* w = &wbuf[k*64];
    float4 Wv[16];
    #pragma unroll
    for(int q=0;q<16;q++) Wv[q] = *(const float4*)&w[q*4];
    #pragma unroll
    for(int q=0;q<16;q++){
      s64[q*4+0]=fmaf(tv,Wv[q].x,s64[q*4+0]);
      s64[q*4+1]=fmaf(tv,Wv[q].y,s64[q*4+1]);
      s64[q*4+2]=fmaf(tv,Wv[q].z,s64[q*4+2]);
      s64[q*4+3]=fmaf(tv,Wv[q].w,s64[q*4+3]);
    }
  }

  const float* rw1=wp.p[set?28:24]; const float* rb1=wp.p[set?29:25];
  const float* rw2=wp.p[set?30:26];
  float qacc = wp.p[set?31:27][0];
  for(int c=0;c<4;c++){
    __syncthreads();
    for(int i=tid;i<1024;i+=TBW){
      int k=i>>4, q4=i&15;
      *(float4*)&wbuf[k*64+q4*4] = *(const float4*)&rw1[k*256+c*64+q4*4];
    }
    __syncthreads();
    float hh[64];
    #pragma unroll
    for(int n=0;n<64;n++) hh[n]=rb1[c*64+n];
    #pragma unroll
    for(int k=0;k<64;k++){          // static s64 index (fully unrolled)
      float sv = s64[k];
      const float* w = &wbuf[k*64];
      float4 Wv[16];
      #pragma unroll
      for(int q=0;q<16;q++) Wv[q] = *(const float4*)&w[q*4];
      #pragma unroll
      for(int q=0;q<16;q++){
        hh[q*4+0]=fmaf(sv,Wv[q].x,hh[q*4+0]);
        hh[q*4+1]=fmaf(sv,Wv[q].y,hh[q*4+1]);
        hh[q*4+2]=fmaf(sv,Wv[q].z,hh[q*4+2]);
        hh[q*4+3]=fmaf(sv,Wv[q].w,hh[q*4+3]);
      }
    }
    #pragma unroll
    for(int n=0;n<64;n++) qacc=fmaf(fmaxf(hh[n],0.f),rw2[c*64+n],qacc);
  }
  if (live) out[set*B + s] = qacc;
}

// =====================================================================
// Fallback: round-10 monolithic kernel (proven) if ws too small
// =====================================================================
#define TB 64
#define R_MPH 68
#define R_EF  260
#define R_T   356
#define NROW  420

extern "C" __global__ void __launch_bounds__(TB, 1)
critic_mech(const float* __restrict__ obs, const float* __restrict__ act,
            const float* __restrict__ ag, const float* __restrict__ g,
            WPtrs wp, float* __restrict__ out, int B)
{
  extern __shared__ float L[];
  const int tid = threadIdx.x;
  const int s = blockIdx.x*TB + tid;
  if (s >= B) return;
  #define LDR(r) L[(r)*TB + tid]
  for(int k=0;k<4;k++)  LDR(k)      = act[s*4+k];
  for(int k=0;k<55;k++) LDR(4+k)    = obs[s*55+k];
  for(int k=0;k<9;k++)  LDR(59+k)   = g[s*9+k] - ag[s*9+k];
  {
    const float* W1=wp.p[0]; const float* B1=wp.p[1];
    const float* W2=wp.p[2]; const float* B2=wp.p[3];
    for(int e=0;e<6;e++){
      float xin[8];
      #pragma unroll
      for(int i=0;i<2;i++) xin[i]   = LDR(59 + PRED[e][i]);
      #pragma unroll
      for(int i=0;i<3;i++) xin[2+i] = LDR(4 + 10 + 15*EDG[e][0] + i);
      #pragma unroll
      for(int i=0;i<3;i++) xin[5+i] = LDR(4 + 10 + 15*EDG[e][1] + i);
      float o32[32];
      #pragma unroll
      for(int m=0;m<32;m++) o32[m]=B2[m];
      for(int c=0;c<4;c++){
        float hh[64];
        #pragma unroll
        for(int n=0;n<64;n++) hh[n]=B1[c*64+n];
        #pragma unroll
        for(int k=0;k<8;k++){
          const float* w = W1 + k*256 + c*64;
          #pragma unroll
          for(int n=0;n<64;n++) hh[n]=fmaf(xin[k],w[n],hh[n]);
        }
        #pragma unroll
        for(int n=0;n<64;n++) LDR(R_T+n)=fmaxf(hh[n],0.f);
        for(int n=0;n<64;n++){
          float hv=LDR(R_T+n);
          const float* w = W2 + (c*64+n)*32;
          #pragma unroll
          for(int m=0;m<32;m++) o32[m]=fmaf(hv,w[m],o32[m]);
        }
      }
      #pragma unroll
      for(int m=0;m<32;m++) LDR(R_MPH+e*32+m)=o32[m];
    }
  }
  for(int o=0;o<3;o++){
    float x0[32], x1[32];
    #pragma unroll
    for(int k=0;k<32;k++){
      x0[k]=LDR(R_MPH+INCM[o][0]*32+k);
      x1[k]=LDR(R_MPH+INCM[o][1]*32+k);
    }
    float q0=wp.p[5][0], q1=wp.p[5][0], k0=wp.p[7][0], k1=wp.p[7][0];
    #pragma unroll
    for(int k=0;k<32;k++){
      q0=fmaf(x0[k],wp.p[4][k],q0); q1=fmaf(x1[k],wp.p[4][k],q1);
      k0=fmaf(x0[k],wp.p[6][k],k0); k1=fmaf(x1[k],wp.p[6][k],k1);
    }
    float v0[32], v1[32];
    #pragma unroll
    for(int n=0;n<32;n++){ v0[n]=wp.p[9][n]; v1[n]=wp.p[9][n]; }
    #pragma unroll
    for(int k=0;k<32;k++){
      const float* w = wp.p[8] + k*32;
      #pragma unroll
      for(int n=0;n<32;n++){ v0[n]=fmaf(x0[k],w[n],v0[n]); v1[n]=fmaf(x1[k],w[n],v1[n]); }
    }
    float s00=q0*k0, s01=q0*k1, s10=q1*k0, s11=q1*k1;
    float m0=fmaxf(s00,s01), m1=fmaxf(s10,s11);
    float e00=expf(s00-m0), e01=expf(s01-m0), e10=expf(s10-m1), e11=expf(s11-m1);
    float d0=e00+e01, d1=e10+e11;
    float a00=e00/d0, a01=e01/d0, a10=e10/d1, a11=e11/d1;
    #pragma unroll
    for(int n=0;n<32;n++)
      LDR(R_EF+o*32+n) = (a00*v0[n]+a01*v1[n]) + (a10*v0[n]+a11*v1[n]);
  }
  for(int set=0; set<2; set++){
    const float* pw1=wp.p[set?14:10]; const float* pb1=wp.p[set?15:11];
    const float* pw2=wp.p[set?16:12]; const float* pb2=wp.p[set?17:13];
    for(int j=0;j<3;j++){
      float o64[64];
      #pragma unroll
      for(int n=0;n<64;n++) o64[n]=pb2[n];
      for(int c=0;c<4;c++){
        float hh[64];
        #pragma unroll
        for(int n=0;n<64;n++) hh[n]=pb1[c*64+n];
        for(int k=0;k<61;k++){
          int row = (k<14) ? k : (k<29) ? (4+10+15*j+(k-14)) : (R_EF+32*j+(k-29));
          float xv = LDR(row);
          const float* w = pw1 + k*256 + c*64;
          #pragma unroll
          for(int n=0;n<64;n++) hh[n]=fmaf(xv,w[n],hh[n]);
        }
        #pragma unroll
        for(int n=0;n<64;n++) LDR(R_T+n)=fmaxf(hh[n],0.f);
        for(int n=0;n<64;n++){
          float hv=LDR(R_T+n);
          const float* w = pw2 + (c*64+n)*64;
          #pragma unroll
          for(int m=0;m<64;m++) o64[m]=fmaf(hv,w[m],o64[m]);
        }
      }
      #pragma unroll
      for(int n=0;n<64;n++) LDR(R_MPH+j*64+n)=fmaxf(o64[n],0.f);
    }
    float qn[3], kn[3];
    #pragma unroll
    for(int j=0;j<3;j++){
      float qq=wp.p[19][0], kk=wp.p[21][0];
      for(int n=0;n<64;n++){
        float hv=LDR(R_MPH+j*64+n);
        qq=fmaf(hv,wp.p[18][n],qq);
        kk=fmaf(hv,wp.p[20][n],kk);
      }
      qn[j]=qq; kn[j]=kk;
    }
    float cw0=0.f,cw1=0.f,cw2=0.f;
    #pragma unroll
    for(int i=0;i<3;i++){
      float t0=qn[i]*kn[0], t1=qn[i]*kn[1], t2=qn[i]*kn[2];
      float mm=fmaxf(fmaxf(t0,t1),t2);
      float e0=expf(t0-mm), e1=expf(t1-mm), e2=expf(t2-mm);
      float dd=e0+e1+e2;
      cw0+=e0/dd; cw1+=e1/dd; cw2+=e2/dd;
    }
    #pragma unroll
    for(int n=0;n<64;n++)
      LDR(R_T+n) = cw0*LDR(R_MPH+0*64+n) + cw1*LDR(R_MPH+1*64+n) + cw2*LDR(R_MPH+2*64+n);
    float s64[64];
    #pragma unroll
    for(int n=0;n<64;n++) s64[n] = 3.f*wp.p[23][n];
    for(int k=0;k<64;k++){
      float xv = LDR(R_T+k);
      const float* w = wp.p[22] + k*64;
      #pragma unroll
      for(int n=0;n<64;n++) s64[n]=fmaf(xv,w[n],s64[n]);
    }
    #pragma unroll
    for(int n=0;n<64;n++) LDR(R_T+n)=s64[n];
    const float* rw1=wp.p[set?28:24]; const float* rb1=wp.p[set?29:25];
    const float* rw2=wp.p[set?30:26];
    float qacc = wp.p[set?31:27][0];
    for(int c=0;c<4;c++){
      float hh[64];
      #pragma unroll
      for(int n=0;n<64;n++) hh[n]=rb1[c*64+n];
      for(int k=0;k<64;k++){
        float sv=LDR(R_T+k);
        const float* w = rw1 + k*256 + c*64;
        #pragma unroll
        for(int n=0;n<64;n++) hh[n]=fmaf(sv,w[n],hh[n]);
      }
      #pragma unroll
      for(int n=0;n<64;n++) qacc=fmaf(fmaxf(hh[n],0.f),rw2[c*64+n],qacc);
    }
    out[set*B + s] = qacc;
  }
  #undef LDR
}

extern "C" __global__ void sentinel_fill(float* out, int n, float val){
  int i = blockIdx.x*blockDim.x + threadIdx.x;
  for(; i<n; i += gridDim.x*blockDim.x) out[i] = val;
}

extern "C" void kernel_launch(void* const* d_in, const int* in_sizes, int n_in,
                              void* d_out, int out_size, void* d_ws, size_t ws_size,
                              hipStream_t stream) {
  float* out = (float*)d_out;
  if (n_in != 36) { hipLaunchKernelGGL(sentinel_fill, dim3(256), dim3(256), 0, stream, out, out_size, 9000.0f); return; }
  const int B = in_sizes[0] / 55;
  if (out_size != 2*B) { hipLaunchKernelGGL(sentinel_fill, dim3(256), dim3(256), 0, stream, out, out_size, 7777.0f); return; }

  const float* obs = (const float*)d_in[0];
  const float* act = (const float*)d_in[1];
  const float* ag  = (const float*)d_in[2];
  const float* g   = (const float*)d_in[3];
  WPtrs wp;
  for(int i=0;i<32;i++) wp.p[i] = (const float*)d_in[4+i];

  const size_t ws_need = (size_t)492 * B * sizeof(float);

  if (ws_size >= ws_need) {
    float* ws = (float*)d_ws;
    const int nbw = (B + TBW - 1)/TBW;
    hipLaunchKernelGGL(pass_mpea, dim3(nbw, 3), dim3(TBW), 0, stream, obs, ag, g, wp, ws, B);
    hipLaunchKernelGGL(pass_phi,  dim3(nbw, 6), dim3(TBW), 0, stream, obs, act, wp, ws, B);
    hipLaunchKernelGGL(pass_rho,  dim3(nbw, 2), dim3(TBW), 0, stream, wp, ws, out, B);
  } else {
    const int nb = (B + TB - 1)/TB;
    const size_t lds_bytes = (size_t)NROW * TB * sizeof(float);
    hipLaunchKernelGGL(critic_mech, dim3(nb), dim3(TB), lds_bytes, stream,
                       obs, act, ag, g, wp, out, B);
  }
}

// Round 27
// 841.204 us; speedup vs baseline: 13.7880x; 13.7880x over previous
//
#include <hip/hip_runtime.h>

typedef unsigned short u16;
typedef unsigned int u32;

#define TBW 128   // threads per block (2 waves)

// ---- graph constants (verbatim from reference) ----
__device__ static constexpr int PRED[6][2] = {{0,3},{1,5},{0,4},{2,7},{1,6},{2,8}};
__device__ static constexpr int EDG [6][2] = {{0,1},{0,2},{1,0},{1,2},{2,0},{2,1}};
__device__ static constexpr int INCM[3][2] = {{2,4},{0,5},{1,3}};

struct WPtrs { const float* p[32]; };

// ws layout (floats): ef [96][B] @0 ; h [384][B] @96B ; qk [12][B] @480B ; total 492*B
// r27 = r25 verbatim (r26's register-resident xin spilled 31GB scratch: reverted).
// Register-pressure cliff confirmed 3x (r12/r18/r26): allocator caps ~130 arch
// VGPRs at 2-block residency; activations MUST stay in LDS columns.

// =====================================================================
// Pass MPEA (fused): grid (B/TBW, 3), o = blockIdx.y.
// r25: register batching in both layers (r24-proven technique).
// =====================================================================
extern "C" __global__ void __launch_bounds__(TBW, 2)
pass_mpea(const float* __restrict__ obs, const float* __restrict__ ag,
          const float* __restrict__ g, WPtrs wp, float* __restrict__ ws, int B)
{
  __shared__ float xs[18*TBW];
  __shared__ float x0b[32*TBW];
  __shared__ float wbuf[512];
  __shared__ float wv[1024];
  __shared__ float hst[4*TBW];
  const int tid = threadIdx.x;
  const int s = blockIdx.x*TBW + tid;
  const int o = blockIdx.y;
  const bool live = (s < B);

  if (live) {
    #pragma unroll
    for(int k=0;k<9;k++) xs[k*TBW+tid] = g[s*9+k] - ag[s*9+k];
    #pragma unroll
    for(int oo=0;oo<3;oo++)
      #pragma unroll
      for(int i=0;i<3;i++) xs[(9+oo*3+i)*TBW+tid] = obs[s*55+10+15*oo+i];
  }
  for(int i=tid;i<256;i+=TBW)
    *(float4*)&wv[i*4] = *(const float4*)&wp.p[8][i*4];

  const float* W1=wp.p[0]; const float* B1=wp.p[1];
  const float* W2=wp.p[2]; const float* B2=wp.p[3];
  float* ef = ws;

  float q0,k0,q1,k1;
  float o32[32];

  #pragma unroll
  for(int slot=0;slot<2;slot++){
    const int e = INCM[o][slot];
    #pragma unroll
    for(int m=0;m<32;m++) o32[m]=B2[m];

    for(int c16=0;c16<16;c16++){
      __syncthreads();
      for(int i=tid;i<32;i+=TBW){
        int k=i>>2, q=i&3;
        *(float4*)&wbuf[k*16+q*4] = *(const float4*)&W1[k*256 + c16*16 + q*4];
      }
      __syncthreads();
      // layer 1 with distance-1 register prefetch (8 k-iters)
      float hh[16];
      #pragma unroll
      for(int n=0;n<16;n++) hh[n]=B1[c16*16+n];
      {
        float4 w0 = *(const float4*)&wbuf[0];
        float4 w1 = *(const float4*)&wbuf[4];
        float4 w2 = *(const float4*)&wbuf[8];
        float4 w3 = *(const float4*)&wbuf[12];
        #pragma unroll
        for(int k=0;k<8;k++){
          const int row = (k<2) ? PRED[e][k] : (k<5) ? (9+3*EDG[e][0]+(k-2)) : (9+3*EDG[e][1]+(k-5));
          float xv = xs[row*TBW+tid];
          float4 n0,n1,n2,n3;
          if (k<7){
            n0 = *(const float4*)&wbuf[(k+1)*16+0];
            n1 = *(const float4*)&wbuf[(k+1)*16+4];
            n2 = *(const float4*)&wbuf[(k+1)*16+8];
            n3 = *(const float4*)&wbuf[(k+1)*16+12];
          } else { n0=w0; n1=w1; n2=w2; n3=w3; }
          hh[0]=fmaf(xv,w0.x,hh[0]);  hh[1]=fmaf(xv,w0.y,hh[1]);
          hh[2]=fmaf(xv,w0.z,hh[2]);  hh[3]=fmaf(xv,w0.w,hh[3]);
          hh[4]=fmaf(xv,w1.x,hh[4]);  hh[5]=fmaf(xv,w1.y,hh[5]);
          hh[6]=fmaf(xv,w1.z,hh[6]);  hh[7]=fmaf(xv,w1.w,hh[7]);
          hh[8]=fmaf(xv,w2.x,hh[8]);  hh[9]=fmaf(xv,w2.y,hh[9]);
          hh[10]=fmaf(xv,w2.z,hh[10]); hh[11]=fmaf(xv,w2.w,hh[11]);
          hh[12]=fmaf(xv,w3.x,hh[12]); hh[13]=fmaf(xv,w3.y,hh[13]);
          hh[14]=fmaf(xv,w3.z,hh[14]); hh[15]=fmaf(xv,w3.w,hh[15]);
          w0=n0; w1=n1; w2=n2; w3=n3;
        }
      }
      __syncthreads();
      for(int i=tid;i<128;i+=TBW){
        int t=i>>3, q=i&7;
        *(float4*)&wbuf[t*32+q*4] = *(const float4*)&W2[(c16*16+t)*32 + q*4];
      }
      __syncthreads();
      // layer 2: batch the 8-float4 row, then 32 FMAs
      #pragma unroll
      for(int g4=0;g4<4;g4++){
        #pragma unroll
        for(int t=0;t<4;t++) hst[t*TBW+tid]=fmaxf(hh[g4*4+t],0.f);
        for(int t=0;t<4;t++){
          float hv=hst[t*TBW+tid];
          const float* w = &wbuf[(g4*4+t)*32];
          float4 Wv[8];
          #pragma unroll
          for(int q=0;q<8;q++) Wv[q] = *(const float4*)&w[q*4];
          #pragma unroll
          for(int q=0;q<8;q++){
            o32[q*4+0]=fmaf(hv,Wv[q].x,o32[q*4+0]);
            o32[q*4+1]=fmaf(hv,Wv[q].y,o32[q*4+1]);
            o32[q*4+2]=fmaf(hv,Wv[q].z,o32[q*4+2]);
            o32[q*4+3]=fmaf(hv,Wv[q].w,o32[q*4+3]);
          }
        }
      }
    }
    float qt=wp.p[5][0], kt=wp.p[7][0];
    #pragma unroll
    for(int k=0;k<32;k++){ qt=fmaf(o32[k],wp.p[4][k],qt); kt=fmaf(o32[k],wp.p[6][k],kt); }
    if(slot==0){
      q0=qt; k0=kt;
      #pragma unroll
      for(int n=0;n<32;n++) x0b[n*TBW+tid]=o32[n];
    } else {
      q1=qt; k1=kt;
    }
  }

  float s00=q0*k0, s01=q0*k1, s10=q1*k0, s11=q1*k1;
  float m0=fmaxf(s00,s01), m1=fmaxf(s10,s11);
  float e00=expf(s00-m0), e01=expf(s01-m0), e10=expf(s10-m1), e11=expf(s11-m1);
  float d0=e00+e01, d1=e10+e11;
  float c0=e00/d0+e10/d1, c1=e01/d0+e11/d1;

  float xm[32];
  #pragma unroll
  for(int n=0;n<32;n++) xm[n] = fmaf(c0, x0b[n*TBW+tid], c1*o32[n]);
  float vt[32];
  #pragma unroll
  for(int n=0;n<32;n++) vt[n] = 2.f*wp.p[9][n];
  #pragma unroll
  for(int g8=0;g8<8;g8++){
    #pragma unroll
    for(int t=0;t<4;t++) hst[t*TBW+tid]=xm[g8*4+t];
    for(int t=0;t<4;t++){
      float a=hst[t*TBW+tid];
      const float* w = &wv[(g8*4+t)*32];
      float4 Wv[8];
      #pragma unroll
      for(int q=0;q<8;q++) Wv[q] = *(const float4*)&w[q*4];
      #pragma unroll
      for(int q=0;q<8;q++){
        vt[q*4+0]=fmaf(a,Wv[q].x,vt[q*4+0]);
        vt[q*4+1]=fmaf(a,Wv[q].y,vt[q*4+1]);
        vt[q*4+2]=fmaf(a,Wv[q].z,vt[q*4+2]);
        vt[q*4+3]=fmaf(a,Wv[q].w,vt[q*4+3]);
      }
    }
  }
  if (live) {
    #pragma unroll
    for(int n=0;n<32;n++) ef[(o*32+n)*B + s] = vt[n];
  }
}

// =====================================================================
// Pass B1 (phi): grid (B/TBW, 6). (r24, proven: reg prefetch + batching)
// =====================================================================
extern "C" __global__ void __launch_bounds__(TBW, 2)
pass_phi(const float* __restrict__ obs, const float* __restrict__ act,
         WPtrs wp, float* __restrict__ ws, int B)
{
  __shared__ float xs[61*TBW];
  __shared__ float wbuf[1024];
  __shared__ float hst[4*TBW];
  const int tid = threadIdx.x;
  const int s = blockIdx.x*TBW + tid;
  const int combo = blockIdx.y;
  const int set = combo/3, j = combo%3;
  const bool live = (s < B);

  const float* ef = ws;
  float* h  = ws + 96*B;
  float* qk = ws + 480*B;

  if (live) {
    #pragma unroll
    for(int k=0;k<4;k++)  xs[k*TBW+tid]      = act[s*4+k];
    #pragma unroll
    for(int k=0;k<10;k++) xs[(4+k)*TBW+tid]  = obs[s*55+k];
    #pragma unroll
    for(int k=0;k<15;k++) xs[(14+k)*TBW+tid] = obs[s*55+10+15*j+k];
    #pragma unroll
    for(int k=0;k<32;k++) xs[(29+k)*TBW+tid] = ef[(j*32+k)*B + s];
  }

  const float* pw1 = wp.p[set?14:10]; const float* pb1 = wp.p[set?15:11];
  const float* pw2 = wp.p[set?16:12]; const float* pb2 = wp.p[set?17:13];

  float o64[64];
  #pragma unroll
  for(int n=0;n<64;n++) o64[n]=pb2[n];

  for(int c16=0;c16<16;c16++){
    __syncthreads();
    for(int i=tid;i<244;i+=TBW){
      int k=i>>2, q=i&3;
      *(float4*)&wbuf[k*16+q*4] = *(const float4*)&pw1[k*256 + c16*16 + q*4];
    }
    __syncthreads();
    float hh[16];
    #pragma unroll
    for(int n=0;n<16;n++) hh[n]=pb1[c16*16+n];
    float4 w0 = *(const float4*)&wbuf[0];
    float4 w1 = *(const float4*)&wbuf[4];
    float4 w2 = *(const float4*)&wbuf[8];
    float4 w3 = *(const float4*)&wbuf[12];
    for(int k=0;k<61;k++){
      float xv = xs[k*TBW+tid];
      float4 n0,n1,n2,n3;
      if (k<60){
        n0 = *(const float4*)&wbuf[(k+1)*16+0];
        n1 = *(const float4*)&wbuf[(k+1)*16+4];
        n2 = *(const float4*)&wbuf[(k+1)*16+8];
        n3 = *(const float4*)&wbuf[(k+1)*16+12];
      } else { n0=w0; n1=w1; n2=w2; n3=w3; }
      hh[0]=fmaf(xv,w0.x,hh[0]);  hh[1]=fmaf(xv,w0.y,hh[1]);
      hh[2]=fmaf(xv,w0.z,hh[2]);  hh[3]=fmaf(xv,w0.w,hh[3]);
      hh[4]=fmaf(xv,w1.x,hh[4]);  hh[5]=fmaf(xv,w1.y,hh[5]);
      hh[6]=fmaf(xv,w1.z,hh[6]);  hh[7]=fmaf(xv,w1.w,hh[7]);
      hh[8]=fmaf(xv,w2.x,hh[8]);  hh[9]=fmaf(xv,w2.y,hh[9]);
      hh[10]=fmaf(xv,w2.z,hh[10]); hh[11]=fmaf(xv,w2.w,hh[11]);
      hh[12]=fmaf(xv,w3.x,hh[12]); hh[13]=fmaf(xv,w3.y,hh[13]);
      hh[14]=fmaf(xv,w3.z,hh[14]); hh[15]=fmaf(xv,w3.w,hh[15]);
      w0=n0; w1=n1; w2=n2; w3=n3;
    }
    __syncthreads();
    for(int i=tid;i<256;i+=TBW){
      int t=i>>4, q=i&15;
      *(float4*)&wbuf[t*64+q*4] = *(const float4*)&pw2[(c16*16+t)*64 + q*4];
    }
    __syncthreads();
    #pragma unroll
    for(int g=0;g<4;g++){
      #pragma unroll
      for(int t=0;t<4;t++) hst[t*TBW+tid]=fmaxf(hh[g*4+t],0.f);
      for(int t=0;t<4;t++){
        float hv=hst[t*TBW+tid];
        const float* w = &wbuf[(g*4+t)*64];
        float4 Wv[16];
        #pragma unroll
        for(int q=0;q<16;q++) Wv[q] = *(const float4*)&w[q*4];
        #pragma unroll
        for(int q=0;q<16;q++){
          o64[q*4+0]=fmaf(hv,Wv[q].x,o64[q*4+0]);
          o64[q*4+1]=fmaf(hv,Wv[q].y,o64[q*4+1]);
          o64[q*4+2]=fmaf(hv,Wv[q].z,o64[q*4+2]);
          o64[q*4+3]=fmaf(hv,Wv[q].w,o64[q*4+3]);
        }
      }
    }
  }
  if (live) {
    float qj=wp.p[19][0], kj=wp.p[21][0];
    #pragma unroll
    for(int n=0;n<64;n++){
      float hv = fmaxf(o64[n],0.f);
      h[(combo*64+n)*B + s] = hv;
      qj = fmaf(hv, wp.p[18][n], qj);
      kj = fmaf(hv, wp.p[20][n], kj);
    }
    qk[(combo*2+0)*B + s] = qj;
    qk[(combo*2+1)*B + s] = kj;
  }
}

// =====================================================================
// Pass B2 (rho): grid (B/TBW, 2). (r25, proven: full-row reg batching)
// =====================================================================
extern "C" __global__ void __launch_bounds__(TBW, 2)
pass_rho(WPtrs wp, const float* __restrict__ ws, float* __restrict__ out, int B)
{
  __shared__ float wbuf[4096];
  __shared__ float hst[16*TBW];
  const int tid = threadIdx.x;
  const int s = blockIdx.x*TBW + tid;
  const int set = blockIdx.y;
  const bool live = (s < B);

  const float* h  = ws + 96*B;
  const float* qk = ws + 480*B;

  for(int i=tid;i<1024;i+=TBW)
    *(float4*)&wbuf[i*4] = *(const float4*)&wp.p[22][i*4];
  __syncthreads();

  float cw0=0.f, cw1=0.f, cw2=0.f;
  float t64[64];
  if (live) {
    float qn[3], kn[3];
    #pragma unroll
    for(int t=0;t<3;t++){
      qn[t] = qk[((set*3+t)*2+0)*B + s];
      kn[t] = qk[((set*3+t)*2+1)*B + s];
    }
    #pragma unroll
    for(int i=0;i<3;i++){
      float t0=qn[i]*kn[0], t1=qn[i]*kn[1], t2=qn[i]*kn[2];
      float mm=fmaxf(fmaxf(t0,t1),t2);
      float e0=expf(t0-mm), e1=expf(t1-mm), e2=expf(t2-mm);
      float dd=e0+e1+e2;
      cw0 += e0/dd; cw1 += e1/dd; cw2 += e2/dd;
    }
    #pragma unroll
    for(int n=0;n<64;n++){
      t64[n] = cw0*h[((set*3+0)*64+n)*B+s]
             + cw1*h[((set*3+1)*64+n)*B+s]
             + cw2*h[((set*3+2)*64+n)*B+s];
    }
  } else {
    #pragma unroll
    for(int n=0;n<64;n++) t64[n]=0.f;
  }

  float s64[64];
  #pragma unroll
  for(int n=0;n<64;n++) s64[n] = 3.f*wp.p[23][n];
  #pragma unroll
  for(int g4=0;g4<4;g4++){
    #pragma unroll
    for(int t=0;t<16;t++) hst[t*TBW+tid]=t64[g4*16+t];
    for(int t=0;t<16;t++){
      float tv=hst[t*TBW+tid];
      const float* w = &wbuf[(g4*16+t)*64];
      float4 Wv[16];
      #pragma unroll
      for(int q=0;q<16;q++) Wv[q] = *(const float4*)&w[q*4];
      #pragma unroll
      for(int q=0;q<16;q++){
        s64[q*4+0]=fmaf(tv,Wv[q].x,s64[q*4+0]);
        s64[q*4+1]=fmaf(tv,Wv[q].y,s64[q*4+1]);
        s64[q*4+2]=fmaf(tv,Wv[q].z,s64[q*4+2]);
        s64[q*4+3]=fmaf(tv,Wv[q].w,s64[q*4+3]);
      }
    }
  }

  const float* rw1=wp.p[set?28:24]; const float* rb1=wp.p[set?29:25];
  const float* rw2=wp.p[set?30:26];
  float qacc = wp.p[set?31:27][0];
  for(int c=0;c<4;c++){
    __syncthreads();
    for(int i=tid;i<1024;i+=TBW){
      int k=i>>4, q4=i&15;
      *(float4*)&wbuf[k*64+q4*4] = *(const float4*)&rw1[k*256+c*64+q4*4];
    }
    __syncthreads();
    float hh[64];
    #pragma unroll
    for(int n=0;n<64;n++) hh[n]=rb1[c*64+n];
    #pragma unroll
    for(int g4=0;g4<4;g4++){
      #pragma unroll
      for(int t=0;t<16;t++) hst[t*TBW+tid]=s64[g4*16+t];
      for(int t=0;t<16;t++){
        float sv=hst[t*TBW+tid];
        const float* w = &wbuf[(g4*16+t)*64];
        float4 Wv[16];
        #pragma unroll
        for(int q=0;q<16;q++) Wv[q] = *(const float4*)&w[q*4];
        #pragma unroll
        for(int q=0;q<16;q++){
          hh[q*4+0]=fmaf(sv,Wv[q].x,hh[q*4+0]);
          hh[q*4+1]=fmaf(sv,Wv[q].y,hh[q*4+1]);
          hh[q*4+2]=fmaf(sv,Wv[q].z,hh[q*4+2]);
          hh[q*4+3]=fmaf(sv,Wv[q].w,hh[q*4+3]);
        }
      }
    }
    #pragma unroll
    for(int n=0;n<64;n++) qacc=fmaf(fmaxf(hh[n],0.f),rw2[c*64+n],qacc);
  }
  if (live) out[set*B + s] = qacc;
}

// =====================================================================
// Fallback: round-10 monolithic kernel (proven) if ws too small
// =====================================================================
#define TB 64
#define R_MPH 68
#define R_EF  260
#define R_T   356
#define NROW  420

extern "C" __global__ void __launch_bounds__(TB, 1)
critic_mech(const float* __restrict__ obs, const float* __restrict__ act,
            const float* __restrict__ ag, const float* __restrict__ g,
            WPtrs wp, float* __restrict__ out, int B)
{
  extern __shared__ float L[];
  const int tid = threadIdx.x;
  const int s = blockIdx.x*TB + tid;
  if (s >= B) return;
  #define LDR(r) L[(r)*TB + tid]
  for(int k=0;k<4;k++)  LDR(k)      = act[s*4+k];
  for(int k=0;k<55;k++) LDR(4+k)    = obs[s*55+k];
  for(int k=0;k<9;k++)  LDR(59+k)   = g[s*9+k] - ag[s*9+k];
  {
    const float* W1=wp.p[0]; const float* B1=wp.p[1];
    const float* W2=wp.p[2]; const float* B2=wp.p[3];
    for(int e=0;e<6;e++){
      float xin[8];
      #pragma unroll
      for(int i=0;i<2;i++) xin[i]   = LDR(59 + PRED[e][i]);
      #pragma unroll
      for(int i=0;i<3;i++) xin[2+i] = LDR(4 + 10 + 15*EDG[e][0] + i);
      #pragma unroll
      for(int i=0;i<3;i++) xin[5+i] = LDR(4 + 10 + 15*EDG[e][1] + i);
      float o32[32];
      #pragma unroll
      for(int m=0;m<32;m++) o32[m]=B2[m];
      for(int c=0;c<4;c++){
        float hh[64];
        #pragma unroll
        for(int n=0;n<64;n++) hh[n]=B1[c*64+n];
        #pragma unroll
        for(int k=0;k<8;k++){
          const float* w = W1 + k*256 + c*64;
          #pragma unroll
          for(int n=0;n<64;n++) hh[n]=fmaf(xin[k],w[n],hh[n]);
        }
        #pragma unroll
        for(int n=0;n<64;n++) LDR(R_T+n)=fmaxf(hh[n],0.f);
        for(int n=0;n<64;n++){
          float hv=LDR(R_T+n);
          const float* w = W2 + (c*64+n)*32;
          #pragma unroll
          for(int m=0;m<32;m++) o32[m]=fmaf(hv,w[m],o32[m]);
        }
      }
      #pragma unroll
      for(int m=0;m<32;m++) LDR(R_MPH+e*32+m)=o32[m];
    }
  }
  for(int o=0;o<3;o++){
    float x0[32], x1[32];
    #pragma unroll
    for(int k=0;k<32;k++){
      x0[k]=LDR(R_MPH+INCM[o][0]*32+k);
      x1[k]=LDR(R_MPH+INCM[o][1]*32+k);
    }
    float q0=wp.p[5][0], q1=wp.p[5][0], k0=wp.p[7][0], k1=wp.p[7][0];
    #pragma unroll
    for(int k=0;k<32;k++){
      q0=fmaf(x0[k],wp.p[4][k],q0); q1=fmaf(x1[k],wp.p[4][k],q1);
      k0=fmaf(x0[k],wp.p[6][k],k0); k1=fmaf(x1[k],wp.p[6][k],k1);
    }
    float v0[32], v1[32];
    #pragma unroll
    for(int n=0;n<32;n++){ v0[n]=wp.p[9][n]; v1[n]=wp.p[9][n]; }
    #pragma unroll
    for(int k=0;k<32;k++){
      const float* w = wp.p[8] + k*32;
      #pragma unroll
      for(int n=0;n<32;n++){ v0[n]=fmaf(x0[k],w[n],v0[n]); v1[n]=fmaf(x1[k],w[n],v1[n]); }
    }
    float s00=q0*k0, s01=q0*k1, s10=q1*k0, s11=q1*k1;
    float m0=fmaxf(s00,s01), m1=fmaxf(s10,s11);
    float e00=expf(s00-m0), e01=expf(s01-m0), e10=expf(s10-m1), e11=expf(s11-m1);
    float d0=e00+e01, d1=e10+e11;
    float a00=e00/d0, a01=e01/d0, a10=e10/d1, a11=e11/d1;
    #pragma unroll
    for(int n=0;n<32;n++)
      LDR(R_EF+o*32+n) = (a00*v0[n]+a01*v1[n]) + (a10*v0[n]+a11*v1[n]);
  }
  for(int set=0; set<2; set++){
    const float* pw1=wp.p[set?14:10]; const float* pb1=wp.p[set?15:11];
    const float* pw2=wp.p[set?16:12]; const float* pb2=wp.p[set?17:13];
    for(int j=0;j<3;j++){
      float o64[64];
      #pragma unroll
      for(int n=0;n<64;n++) o64[n]=pb2[n];
      for(int c=0;c<4;c++){
        float hh[64];
        #pragma unroll
        for(int n=0;n<64;n++) hh[n]=pb1[c*64+n];
        for(int k=0;k<61;k++){
          int row = (k<14) ? k : (k<29) ? (4+10+15*j+(k-14)) : (R_EF+32*j+(k-29));
          float xv = LDR(row);
          const float* w = pw1 + k*256 + c*64;
          #pragma unroll
          for(int n=0;n<64;n++) hh[n]=fmaf(xv,w[n],hh[n]);
        }
        #pragma unroll
        for(int n=0;n<64;n++) LDR(R_T+n)=fmaxf(hh[n],0.f);
        for(int n=0;n<64;n++){
          float hv=LDR(R_T+n);
          const float* w = pw2 + (c*64+n)*64;
          #pragma unroll
          for(int m=0;m<64;m++) o64[m]=fmaf(hv,w[m],o64[m]);
        }
      }
      #pragma unroll
      for(int n=0;n<64;n++) LDR(R_MPH+j*64+n)=fmaxf(o64[n],0.f);
    }
    float qn[3], kn[3];
    #pragma unroll
    for(int j=0;j<3;j++){
      float qq=wp.p[19][0], kk=wp.p[21][0];
      for(int n=0;n<64;n++){
        float hv=LDR(R_MPH+j*64+n);
        qq=fmaf(hv,wp.p[18][n],qq);
        kk=fmaf(hv,wp.p[20][n],kk);
      }
      qn[j]=qq; kn[j]=kk;
    }
    float cw0=0.f,cw1=0.f,cw2=0.f;
    #pragma unroll
    for(int i=0;i<3;i++){
      float t0=qn[i]*kn[0], t1=qn[i]*kn[1], t2=qn[i]*kn[2];
      float mm=fmaxf(fmaxf(t0,t1),t2);
      float e0=expf(t0-mm), e1=expf(t1-mm), e2=expf(t2-mm);
      float dd=e0+e1+e2;
      cw0+=e0/dd; cw1+=e1/dd; cw2+=e2/dd;
    }
    #pragma unroll
    for(int n=0;n<64;n++)
      LDR(R_T+n) = cw0*LDR(R_MPH+0*64+n) + cw1*LDR(R_MPH+1*64+n) + cw2*LDR(R_MPH+2*64+n);
    float s64[64];
    #pragma unroll
    for(int n=0;n<64;n++) s64[n] = 3.f*wp.p[23][n];
    for(int k=0;k<64;k++){
      float xv = LDR(R_T+k);
      const float* w = wp.p[22] + k*64;
      #pragma unroll
      for(int n=0;n<64;n++) s64[n]=fmaf(xv,w[n],s64[n]);
    }
    #pragma unroll
    for(int n=0;n<64;n++) LDR(R_T+n)=s64[n];
    const float* rw1=wp.p[set?28:24]; const float* rb1=wp.p[set?29:25];
    const float* rw2=wp.p[set?30:26];
    float qacc = wp.p[set?31:27][0];
    for(int c=0;c<4;c++){
      float hh[64];
      #pragma unroll
      for(int n=0;n<64;n++) hh[n]=rb1[c*64+n];
      for(int k=0;k<64;k++){
        float sv=LDR(R_T+k);
        const float* w = rw1 + k*256 + c*64;
        #pragma unroll
        for(int n=0;n<64;n++) hh[n]=fmaf(sv,w[n],hh[n]);
      }
      #pragma unroll
      for(int n=0;n<64;n++) qacc=fmaf(fmaxf(hh[n],0.f),rw2[c*64+n],qacc);
    }
    out[set*B + s] = qacc;
  }
  #undef LDR
}

extern "C" __global__ void sentinel_fill(float* out, int n, float val){
  int i = blockIdx.x*blockDim.x + threadIdx.x;
  for(; i<n; i += gridDim.x*blockDim.x) out[i] = val;
}

extern "C" void kernel_launch(void* const* d_in, const int* in_sizes, int n_in,
                              void* d_out, int out_size, void* d_ws, size_t ws_size,
                              hipStream_t stream) {
  float* out = (float*)d_out;
  if (n_in != 36) { hipLaunchKernelGGL(sentinel_fill, dim3(256), dim3(256), 0, stream, out, out_size, 9000.0f); return; }
  const int B = in_sizes[0] / 55;
  if (out_size != 2*B) { hipLaunchKernelGGL(sentinel_fill, dim3(256), dim3(256), 0, stream, out, out_size, 7777.0f); return; }

  const float* obs = (const float*)d_in[0];
  const float* act = (const float*)d_in[1];
  const float* ag  = (const float*)d_in[2];
  const float* g   = (const float*)d_in[3];
  WPtrs wp;
  for(int i=0;i<32;i++) wp.p[i] = (const float*)d_in[4+i];

  const size_t ws_need = (size_t)492 * B * sizeof(float);

  if (ws_size >= ws_need) {
    float* ws = (float*)d_ws;
    const int nbw = (B + TBW - 1)/TBW;
    hipLaunchKernelGGL(pass_mpea, dim3(nbw, 3), dim3(TBW), 0, stream, obs, ag, g, wp, ws, B);
    hipLaunchKernelGGL(pass_phi,  dim3(nbw, 6), dim3(TBW), 0, stream, obs, act, wp, ws, B);
    hipLaunchKernelGGL(pass_rho,  dim3(nbw, 2), dim3(TBW), 0, stream, wp, ws, out, B);
  } else {
    const int nb = (B + TB - 1)/TB;
    const size_t lds_bytes = (size_t)NROW * TB * sizeof(float);
    hipLaunchKernelGGL(critic_mech, dim3(nb), dim3(TB), lds_bytes, stream,
                       obs, act, ag, g, wp, out, B);
  }
}